// Round 1
// baseline (267.488 us; speedup 1.0000x reference)
//
#include <hip/hip_runtime.h>

// TSM (temporal shift): x (128,96,56,56) f32 viewed as (16,8,96,56,56).
//   c in [0,32):  out[b,t] = x[b,t+1]  (zero at t=7)
//   c in [32,64): out[b,t] = x[b,t-1]  (zero at t=0)
//   c in [64,96): out[b,t] = x[b,t]
// Pure plane permutation. Traffic floor: 141.3 MB read + 154.1 MB write.
//
// R3: 16-plane chunk per block. Fold boundaries (32,64) and frame boundaries
// (96) are multiples of 16, so each aligned 16-plane chunk has a uniform
// (shift-group, t) -> uniform delta/zero, no divergence. 16*784 = 12544
// float4 = exactly 49 rounds of 256 threads: no tail predicate. Inner loop
// batches 7 loads before 7 stores for deep MLP. Loads are plain cached
// (m13's 6.29 TB/s copy recipe); stores stay nontemporal (pure stream,
// output is re-poisoned by the harness every iteration anyway).

#define C_TOT   96
#define FOLD    32
#define NFRAME  8
#define HW4     784       // 56*56/4 float4 per plane
#define CHUNK   16        // planes per block (divides 32 and 96)
#define NCHUNKS 768       // 12288 planes / 16
#define ITERS   49        // CHUNK*HW4 / 256

typedef float v4f __attribute__((ext_vector_type(4)));

__global__ __launch_bounds__(256) void tsm_kernel(const v4f* __restrict__ in,
                                                  v4f* __restrict__ out) {
    const int plane0 = blockIdx.x * CHUNK;     // 16-plane aligned
    const int c0 = plane0 % C_TOT;             // in {0,16,32,48,64,80}
    const int t  = (plane0 / C_TOT) % NFRAME;

    int  delta = 0;                            // block-uniform scalars
    bool zero  = false;
    if (c0 < FOLD)          { delta =  C_TOT; zero = (t == NFRAME - 1); }
    else if (c0 < 2 * FOLD) { delta = -C_TOT; zero = (t == 0); }

    const long base = (long)plane0 * HW4;
    v4f* __restrict__ o = out + base + threadIdx.x;

    if (zero) {
        const v4f z = (v4f){0.f, 0.f, 0.f, 0.f};
        #pragma unroll 7
        for (int k = 0; k < ITERS; ++k)
            __builtin_nontemporal_store(z, &o[k * 256]);
    } else {
        const v4f* __restrict__ s = in + base + (long)delta * HW4 + threadIdx.x;
        #pragma unroll 1
        for (int k = 0; k < ITERS; k += 7) {
            const v4f a0 = s[(k + 0) * 256];
            const v4f a1 = s[(k + 1) * 256];
            const v4f a2 = s[(k + 2) * 256];
            const v4f a3 = s[(k + 3) * 256];
            const v4f a4 = s[(k + 4) * 256];
            const v4f a5 = s[(k + 5) * 256];
            const v4f a6 = s[(k + 6) * 256];
            __builtin_nontemporal_store(a0, &o[(k + 0) * 256]);
            __builtin_nontemporal_store(a1, &o[(k + 1) * 256]);
            __builtin_nontemporal_store(a2, &o[(k + 2) * 256]);
            __builtin_nontemporal_store(a3, &o[(k + 3) * 256]);
            __builtin_nontemporal_store(a4, &o[(k + 4) * 256]);
            __builtin_nontemporal_store(a5, &o[(k + 5) * 256]);
            __builtin_nontemporal_store(a6, &o[(k + 6) * 256]);
        }
    }
}

extern "C" void kernel_launch(void* const* d_in, const int* in_sizes, int n_in,
                              void* d_out, int out_size, void* d_ws, size_t ws_size,
                              hipStream_t stream) {
    const v4f* x   = (const v4f*)d_in[0];
    v4f*       out = (v4f*)d_out;
    tsm_kernel<<<NCHUNKS, 256, 0, stream>>>(x, out);
}

// Round 2
// 261.022 us; speedup vs baseline: 1.0248x; 1.0248x over previous
//
#include <hip/hip_runtime.h>

// TSM (temporal shift): x (128,96,56,56) f32 viewed as (16,8,96,56,56).
//   c in [0,32):  out[b,t] = x[b,t+1]  (zero at t=7)
//   c in [32,64): out[b,t] = x[b,t-1]  (zero at t=0)
//   c in [64,96): out[b,t] = x[b,t]
// Pure plane permutation. Traffic floor: 141.3 MB read + 154.1 MB write
// (measured FETCH=69 MB: input is LLC-resident, half the reads hit L3).
//
// R4: fix R3's Little's-law regression. R3 had 768 blocks = 3 blocks/CU =
// 12 waves/CU -> ~1.3 KB outstanding reads/CU -> 2.4 TB/s (measured).
// Now: each 16-plane chunk (uniform shift-group: fold/frame boundaries are
// multiples of 16) is split into 7 slice-blocks of 7 rounds each.
// 49 rounds = 7 slices x 7 rounds, grid = 768*7 = 5376 blocks, 8 resident
// blocks/CU (32 waves, VGPR<=64), each block straight-line:
// 7 batched cached loads -> 7 nontemporal stores. No tail, no divergence.
// NT stores keep the output stream from evicting the LLC-resident input.

#define C_TOT   96
#define FOLD    32
#define NFRAME  8
#define HW4     784       // 56*56/4 float4 per plane
#define CHUNK   16        // planes per chunk (divides 32 and 96)
#define NCHUNKS 768       // 12288 planes / 16
#define SLICES  7         // blocks per chunk
#define RPS     7         // rounds of 256 float4 per slice (7*7*256 = 16*784)
#define NBLOCKS (NCHUNKS * SLICES)

typedef float v4f __attribute__((ext_vector_type(4)));

__global__ __launch_bounds__(256) void tsm_kernel(const v4f* __restrict__ in,
                                                  v4f* __restrict__ out) {
    const int bid   = blockIdx.x;
    const int chunk = bid / SLICES;
    const int slice = bid - chunk * SLICES;

    const int plane0 = chunk * CHUNK;          // 16-plane aligned
    const int c0 = plane0 % C_TOT;             // in {0,16,32,48,64,80}
    const int t  = (plane0 / C_TOT) % NFRAME;

    int  delta = 0;                            // block-uniform scalars
    bool zero  = false;
    if (c0 < FOLD)          { delta =  C_TOT; zero = (t == NFRAME - 1); }
    else if (c0 < 2 * FOLD) { delta = -C_TOT; zero = (t == 0); }

    const long base = (long)plane0 * HW4 + slice * (RPS * 256) + threadIdx.x;
    v4f* __restrict__ o = out + base;

    if (zero) {
        const v4f z = (v4f){0.f, 0.f, 0.f, 0.f};
        __builtin_nontemporal_store(z, &o[0 * 256]);
        __builtin_nontemporal_store(z, &o[1 * 256]);
        __builtin_nontemporal_store(z, &o[2 * 256]);
        __builtin_nontemporal_store(z, &o[3 * 256]);
        __builtin_nontemporal_store(z, &o[4 * 256]);
        __builtin_nontemporal_store(z, &o[5 * 256]);
        __builtin_nontemporal_store(z, &o[6 * 256]);
    } else {
        const v4f* __restrict__ s = in + base + (long)delta * HW4;
        const v4f a0 = s[0 * 256];
        const v4f a1 = s[1 * 256];
        const v4f a2 = s[2 * 256];
        const v4f a3 = s[3 * 256];
        const v4f a4 = s[4 * 256];
        const v4f a5 = s[5 * 256];
        const v4f a6 = s[6 * 256];
        __builtin_nontemporal_store(a0, &o[0 * 256]);
        __builtin_nontemporal_store(a1, &o[1 * 256]);
        __builtin_nontemporal_store(a2, &o[2 * 256]);
        __builtin_nontemporal_store(a3, &o[3 * 256]);
        __builtin_nontemporal_store(a4, &o[4 * 256]);
        __builtin_nontemporal_store(a5, &o[5 * 256]);
        __builtin_nontemporal_store(a6, &o[6 * 256]);
    }
}

extern "C" void kernel_launch(void* const* d_in, const int* in_sizes, int n_in,
                              void* d_out, int out_size, void* d_ws, size_t ws_size,
                              hipStream_t stream) {
    const v4f* x   = (const v4f*)d_in[0];
    v4f*       out = (v4f*)d_out;
    tsm_kernel<<<NBLOCKS, 256, 0, stream>>>(x, out);
}

// Round 3
// 248.678 us; speedup vs baseline: 1.0756x; 1.0496x over previous
//
#include <hip/hip_runtime.h>

// TSM (temporal shift): x (128,96,56,56) f32 viewed as (16,8,96,56,56).
//   c in [0,32):  out[b,t] = x[b,t+1]  (zero at t=7)
//   c in [32,64): out[b,t] = x[b,t-1]  (zero at t=0)
//   c in [64,96): out[b,t] = x[b,t]
// Pure plane permutation. Traffic floor: 141.3 MB read + 154.1 MB write.
//
// R5: revert to R0's proven recipe (NT loads + NT stores: every byte is
// one-touch, cached loads allocate 141 MB of dead data through L2/TCC and
// regressed 58 -> ~80 us in R3/R4), and deepen the load batch: two adjacent
// planes per block. Even-aligned plane pairs never straddle a fold (32,64)
// or frame (96) boundary, so each block stays uniform (no divergence on the
// shift/zero decision). 2*784 = 1568 float4 = 6 full rounds of 256 + 32-lane
// tail: 7 NT loads issued back-to-back before any store (deep MLP), then
// 7 NT stores. 6144 blocks = 24 queued/CU, VGPR < 64 keeps 32 waves/CU.

#define C_TOT   96
#define FOLD    32
#define NFRAME  8
#define HW4     784        // 56*56/4 float4 per plane
#define PAIR4   1568       // 2 planes of float4
#define NBLOCKS 6144       // 12288 planes / 2

typedef float v4f __attribute__((ext_vector_type(4)));

__global__ __launch_bounds__(256) void tsm_kernel(const v4f* __restrict__ in,
                                                  v4f* __restrict__ out) {
    const int plane0 = blockIdx.x * 2;         // even-aligned pair
    const int c = plane0 % C_TOT;
    const int t = (plane0 / C_TOT) % NFRAME;

    int  delta = 0;                            // block-uniform scalars
    bool zero  = false;
    if (c < FOLD)          { delta =  C_TOT; zero = (t == NFRAME - 1); }
    else if (c < 2 * FOLD) { delta = -C_TOT; zero = (t == 0); }

    const long base = (long)plane0 * HW4;
    const int  j    = threadIdx.x;
    v4f* __restrict__ o = out + base + j;
    const bool tail = (j < PAIR4 - 1536);      // 32 lanes

    if (zero) {
        const v4f z = (v4f){0.f, 0.f, 0.f, 0.f};
        __builtin_nontemporal_store(z, &o[0 * 256]);
        __builtin_nontemporal_store(z, &o[1 * 256]);
        __builtin_nontemporal_store(z, &o[2 * 256]);
        __builtin_nontemporal_store(z, &o[3 * 256]);
        __builtin_nontemporal_store(z, &o[4 * 256]);
        __builtin_nontemporal_store(z, &o[5 * 256]);
        if (tail) __builtin_nontemporal_store(z, &o[1536]);
    } else {
        const v4f* __restrict__ s = in + base + (long)delta * HW4 + j;
        const v4f a0 = __builtin_nontemporal_load(&s[0 * 256]);
        const v4f a1 = __builtin_nontemporal_load(&s[1 * 256]);
        const v4f a2 = __builtin_nontemporal_load(&s[2 * 256]);
        const v4f a3 = __builtin_nontemporal_load(&s[3 * 256]);
        const v4f a4 = __builtin_nontemporal_load(&s[4 * 256]);
        const v4f a5 = __builtin_nontemporal_load(&s[5 * 256]);
        v4f a6;
        if (tail) a6 = __builtin_nontemporal_load(&s[1536]);
        __builtin_nontemporal_store(a0, &o[0 * 256]);
        __builtin_nontemporal_store(a1, &o[1 * 256]);
        __builtin_nontemporal_store(a2, &o[2 * 256]);
        __builtin_nontemporal_store(a3, &o[3 * 256]);
        __builtin_nontemporal_store(a4, &o[4 * 256]);
        __builtin_nontemporal_store(a5, &o[5 * 256]);
        if (tail) __builtin_nontemporal_store(a6, &o[1536]);
    }
}

extern "C" void kernel_launch(void* const* d_in, const int* in_sizes, int n_in,
                              void* d_out, int out_size, void* d_ws, size_t ws_size,
                              hipStream_t stream) {
    const v4f* x   = (const v4f*)d_in[0];
    v4f*       out = (v4f*)d_out;
    tsm_kernel<<<NBLOCKS, 256, 0, stream>>>(x, out);
}